// Round 2
// baseline (4434.027 us; speedup 1.0000x reference)
//
#include <hip/hip_runtime.h>

// ============================================================================
// Persistent dataflow kernel for attention-LSTM encoder.
// B=512, T-1=99, N=128, H=256. f32 global I/O, bf16 LDS/MFMA internals.
//
// R7 == R6 resubmitted (R6 bench died with "container failed twice" — no
// compile error, no verification failure, no counters; audit found no
// deadlock/OOB path; treating as infra flake).
//
// R6: R5 spent ~90% of each step waiting (VALUBusy 10%, 4 L3 hops/step:
// flagB -> z1-blocks -> flagZ -> A -> flagA -> B). Remove the z1 sub-phase:
// z1 = [h,c]@W1^T is k-partitioned onto the B-blocks, which already own
// their 16 h/c units for all 32 group batches when their B phase ends.
// Each B-block computes a 16-k partial of z1 for (32 batches x 99 s) via
// 14 MFMAs (W1 k-slice 3.5 KB in LDS, zero-padded K halves) and stores it
// as 64B-aligned coalesced runs. A-blocks sum 32 partials under the same
// flagB wait that already guards h. Chain shrinks to 2 hops:
//   flagB -> A(z1-sum + attention) -> flagA -> B(gates+LSTM+partials) -> flagB
// c no longer crosses blocks (hbuf is h-only, halved). All 512 blocks now
// do identical per-step work (no js<7 straggler asymmetry).
//
// 512 blocks x 256 threads, 2 blocks/CU (LDS ~60KB => all 512 co-resident).
// Each 32-block group is a closed dependency system => deadlock-free.
// z1p single-buffered: reader's loads are consumed (z1s written + barrier)
// before its flagA publish; writers gate on all 32 flagA. hbuf stays
// double-buffered (its prefetch loads are NOT drained before flagA).
// ============================================================================

typedef unsigned int  uint32;
typedef unsigned long long ull;
typedef unsigned short u16;
typedef float  f4  __attribute__((ext_vector_type(4)));
typedef short  s8v __attribute__((ext_vector_type(8)));   // 8 bf16

#define TS 99
#define BB 512
#define NN 128
#define HH 256

__device__ __forceinline__ float bf2f(u16 u){
  union { uint32 i; float f; } v; v.i = ((uint32)u) << 16; return v.f;
}
__device__ __forceinline__ u16 f2bf(float f){
  union { float f; uint32 i; } v; v.f = f;
  uint32 r = v.i + 0x7FFFu + ((v.i >> 16) & 1u);   // RNE (finite values only)
  return (u16)(r >> 16);
}
__device__ __forceinline__ float frcp(float x){ return __builtin_amdgcn_rcpf(x); }
__device__ __forceinline__ float ftanh(float x){
  float t = __expf(2.f * x);
  return 1.f - 2.f * frcp(t + 1.f);
}
__device__ __forceinline__ float fsig(float x){
  return frcp(1.f + __expf(-x));
}

// L3-coherence-point accesses (sc1; bypass per-XCD L2, no cache maintenance)
__device__ __forceinline__ uint32 ld32(const uint32* p){
  return __hip_atomic_load(p, __ATOMIC_RELAXED, __HIP_MEMORY_SCOPE_AGENT);
}
__device__ __forceinline__ ull ld64(const ull* p){
  return __hip_atomic_load(p, __ATOMIC_RELAXED, __HIP_MEMORY_SCOPE_AGENT);
}
__device__ __forceinline__ void st32(uint32* p, uint32 v){
  __hip_atomic_store(p, v, __ATOMIC_RELAXED, __HIP_MEMORY_SCOPE_AGENT);
}
__device__ __forceinline__ void st64(ull* p, ull v){
  __hip_atomic_store(p, v, __ATOMIC_RELAXED, __HIP_MEMORY_SCOPE_AGENT);
}
__device__ __forceinline__ float ldf(const float* p){
  union { uint32 i; float f; } v; v.i = ld32((const uint32*)p); return v.f;
}
__device__ __forceinline__ void stf(float* p, float x){
  union { float f; uint32 i; } v; v.f = x; st32((uint32*)p, v.i);
}

struct KParams {
  const float *in, *W1, *b1, *W2, *b2, *W3, *Wih, *Whh, *bih, *bhh;
  float *out;        // [weighted B*99*128 | encoded B*99*256] f32
  uint32 *flagA;     // [512]  A(t) done -> w published
  uint32 *flagB;     // [16]   counts B-phase completions per group
  u16 *hbuf;         // [2][512][256] bf16: per batch h[256] (double-buffered)
  u16 *wbf;          // [512][128] bf16 (single-buffer, race-safe via flags)
  float *z1p;        // [512][32][112] f32: z1 k-partials [batch][js][s]
};

__global__ __launch_bounds__(256, 2) void enc_kernel(KParams p)
{
  __shared__ __align__(16) u16   z2s[128 * 100];   // z2[n][s] bf16 (+b2)
  __shared__ __align__(16) u16   ubuf[12800];      // in_t[128][100] then Wsl[32][392]
  __shared__ __align__(16) u16   W1sl[112 * 16];   // W1 k-slice: [s pad 112][16 k]
  __shared__ __align__(16) u16   hcn[32 * 16];     // bf16 per-batch [h0..7|c0..7]
  __shared__ __align__(16) float uni[1056];        // z1 partials | e | gates[32][33]
  __shared__ __align__(16) float z1s[100];
  __shared__ __align__(16) float w3s[100];
  __shared__ __align__(16) float b1s[100];
  __shared__ __align__(16) float biasv[32];

  const int tid = threadIdx.x;
  const int blk = blockIdx.x;
  const int bA  = blk;        // A-role batch
  const int bg  = blk >> 5;   // group of 32 batches / 32 blocks
  const int js  = blk & 31;   // B-role unit slice (units js*8 .. js*8+7)

  float* outw = p.out;
  float* oute = p.out + (size_t)BB * TS * NN;

  // wave-role constants (MFMA lane mapping, R4/R5-verified)
  const int wv   = tid >> 6, lane = tid & 63;
  const int mi   = wv & 1,   ni   = wv >> 1;
  const int bb   = bg * 32 + mi * 16 + (lane & 15);
  const int q8   = (lane >> 4) * 8;
  const int m15  = lane & 15;
  const int nr   = ni * 16 + m15;

  // ---------------- prologue ----------------
  {
    const float* src = p.in + (size_t)bA * TS * NN;
    for (int idx = tid; idx < TS * NN; idx += 256) {
      int t = idx >> 7, n = idx & 127;
      ubuf[n * 100 + t] = f2bf(src[idx]);
    }
  }
  __syncthreads();
  {  // z2s[n][s] = b2[s] + sum_t in_t[n][t] * W2[s][t]
    int n = tid >> 1, sc = tid & 1;
    int s0 = sc * 50, s1 = sc ? 99 : 50;
    for (int s = s0; s < s1; ++s) {
      float acc = p.b2[s];
      const float* w2r = p.W2 + s * TS;
      const u16* itr = &ubuf[n * 100];
      for (int t = 0; t + 1 < TS; t += 2) {
        acc = fmaf(bf2f(itr[t]),     w2r[t],     acc);
        acc = fmaf(bf2f(itr[t + 1]), w2r[t + 1], acc);
      }
      acc = fmaf(bf2f(itr[98]), w2r[98], acc);
      z2s[n * 100 + s] = f2bf(acc);
    }
  }
  __syncthreads();
  {  // Wsl[32 rows][392] into ubuf; W1 k-slice; small vectors
    int r = tid >> 3;
    int g = r >> 3, ul = r & 7;
    int grow = g * 256 + js * 8 + ul;
    const float* wihr = p.Wih + (size_t)grow * 128;
    const float* whhr = p.Whh + (size_t)grow * 256;
    for (int k = tid & 7; k < 384; k += 8)
      ubuf[r * 392 + k] = f2bf((k < 128) ? wihr[k] : whhr[k - 128]);
    if (tid < 32) {
      int g2 = tid >> 3, ul2 = tid & 7;
      int gr = g2 * 256 + js * 8 + ul2;
      biasv[tid] = p.bih[gr] + p.bhh[gr];
    }
    // W1sl[s][k]: k<8 -> W1[s][js*8+k] (h part), k>=8 -> W1[s][256+js*8+k-8] (c)
    for (int idx = tid; idx < 112 * 16; idx += 256) {
      int s = idx >> 4, k = idx & 15;
      float v = 0.f;
      if (s < TS) v = p.W1[(size_t)s * 512 + js * 8 + k + ((k >= 8) ? 248 : 0)];
      W1sl[idx] = f2bf(v);
    }
    for (int s = tid; s < 99; s += 256) {
      w3s[s] = p.W3[s];
      b1s[s] = p.b1[s];
    }
  }
  __syncthreads();

  float creg = 0.f;   // LSTM cell state for (lb=tid>>3, ul=tid&7), fp32 forever

  for (int t = 0; t < TS; ++t) {
    const int par = t & 1;

    // ---- single wait: h(t-1) and z1 partials of own group ready ----
    if (t > 0) {
      if (tid == 0) {
        uint32 tgt = 32u * (uint32)t;
        while (ld32(&p.flagB[bg]) < tgt) __builtin_amdgcn_s_sleep(1);
      }
      __syncthreads();
    }

    // ---- prefetch gates h-operand fragments (consumed in B phase) ----
    ull hq0[8], hq1[8];
    {
      const ull* hrow = (const ull*)(p.hbuf + ((size_t)par * BB + bb) * HH);
      #pragma unroll
      for (int ks = 0; ks < 8; ++ks) {
        int ei = ks * 32 + q8;
        hq0[ks] = ld64(hrow + (ei >> 2));
        hq1[ks] = ld64(hrow + (ei >> 2) + 1);
      }
    }

    // ================= A phase: attention for batch bA =================
    // z1[s] = b1[s] + sum over 32 js-partials (coalesced 64B-aligned reads)
    if (t > 0) {
      int s = tid & 127, hf = tid >> 7;   // 2 halves x 16 js-planes each
      if (s < TS) {
        const float* zr = p.z1p + ((size_t)bA * 32 + hf * 16) * 112 + s;
        float vv[16];
        #pragma unroll
        for (int j = 0; j < 16; ++j) vv[j] = ldf(zr + (size_t)j * 112);
        float v0 = 0.f, v1 = 0.f, v2 = 0.f, v3 = 0.f;
        #pragma unroll
        for (int j = 0; j < 16; j += 4) {
          v0 += vv[j]; v1 += vv[j + 1]; v2 += vv[j + 2]; v3 += vv[j + 3];
        }
        uni[hf * 128 + s] = (v0 + v1) + (v2 + v3);
      }
      __syncthreads();
      if (tid < TS) z1s[tid] = b1s[tid] + uni[tid] + uni[128 + tid];
    } else {
      if (tid < TS) z1s[tid] = b1s[tid];   // h=c=0 at t=0
    }
    __syncthreads();

    {  // e[n] = sum_s w3[s] * tanh(z1[s] + z2[n][s])
      int n = tid >> 1, hfb = tid & 1;
      int s0 = hfb * 50, s1 = hfb ? 99 : 50;
      const u16* z2r = &z2s[n * 100];
      float acc = 0.f;
      for (int s = s0; s < s1; ++s) {
        float x = ftanh(z1s[s] + bf2f(z2r[s]));
        acc = fmaf(w3s[s], x, acc);
      }
      uni[tid] = acc;
    }
    __syncthreads();
    // softmax + w, all in wave 0
    float* efin = uni + 256;
    if (tid < 64) {
      float v0 = uni[2 * tid]        + uni[2 * tid + 1];
      float v1 = uni[2 * (tid + 64)] + uni[2 * (tid + 64) + 1];
      efin[tid] = v0; efin[tid + 64] = v1;
      float m = fmaxf(v0, v1);
      for (int off = 32; off; off >>= 1) m = fmaxf(m, __shfl_xor(m, off));
      float sm = __expf(v0 - m) + __expf(v1 - m);
      for (int off = 32; off; off >>= 1) sm += __shfl_xor(sm, off);
      float r = frcp(sm);
      float e0 = efin[2 * tid], e1 = efin[2 * tid + 1];
      const float* xr = p.in + ((size_t)bA * TS + t) * NN + 2 * tid;
      float w0 = __expf(e0 - m) * r * xr[0];
      float w1 = __expf(e1 - m) * r * xr[1];
      float* orow = outw + ((size_t)bA * TS + t) * NN + 2 * tid;
      orow[0] = w0; orow[1] = w1;                      // f32 output
      st32((uint32*)p.wbf + (size_t)bA * 64 + tid,     // bf16 pair, sc1
           (uint32)f2bf(w0) | ((uint32)f2bf(w1) << 16));
    }
    __builtin_amdgcn_s_waitcnt(0);   // drain wave-0 w-stores to L3
    if (tid == 0) st32(&p.flagA[bA], (uint32)(t + 1));

    // ================= B phase: gates+LSTM for (bg, js) =================
    const u16* wslr = &ubuf[nr * 392];
    f4 acc = {0.f, 0.f, 0.f, 0.f};
    #pragma unroll
    for (int ks = 0; ks < 8; ++ks) {   // h-part (fragments already in regs)
      union { ull q[2]; s8v v; } a; a.q[0] = hq0[ks]; a.q[1] = hq1[ks];
      const s8v* bp = (const s8v*)(wslr + 128 + ks * 32 + q8);
      acc = __builtin_amdgcn_mfma_f32_16x16x32_bf16(a.v, *bp, acc, 0, 0, 0);
    }
    if (tid < 32) {   // wait: all A(t) of the group published w
      uint32 tgt = (uint32)(t + 1);
      while (ld32(&p.flagA[bg * 32 + tid]) < tgt) __builtin_amdgcn_s_sleep(1);
    }
    __syncthreads();
    {
      const ull* wrow = (const ull*)(p.wbf + (size_t)bb * NN);
      #pragma unroll
      for (int ks = 0; ks < 4; ++ks) {  // w-part
        int ei = ks * 32 + q8;
        union { ull q[2]; s8v v; } a;
        a.q[0] = ld64(wrow + (ei >> 2));
        a.q[1] = ld64(wrow + (ei >> 2) + 1);
        const s8v* bp = (const s8v*)(wslr + ei);
        acc = __builtin_amdgcn_mfma_f32_16x16x32_bf16(a.v, *bp, acc, 0, 0, 0);
      }
      int mrow = mi * 16 + (lane >> 4) * 4;
      #pragma unroll
      for (int i = 0; i < 4; ++i) uni[(mrow + i) * 33 + nr] = acc[i];
    }
    __syncthreads();
    {  // LSTM pointwise: thread = (lb, ul); hcn gets bf16 h|c directly
      int lb = tid >> 3, ul = tid & 7;
      float iv = uni[lb * 33 + ul]      + biasv[ul];
      float fv = uni[lb * 33 + 8 + ul]  + biasv[8 + ul];
      float gv = uni[lb * 33 + 16 + ul] + biasv[16 + ul];
      float ov = uni[lb * 33 + 24 + ul] + biasv[24 + ul];
      float cn = fsig(fv) * creg + fsig(iv) * ftanh(gv);
      float hn = fsig(ov) * ftanh(cn);
      creg = cn;
      int bb2 = bg * 32 + lb, u = js * 8 + ul;
      oute[((size_t)bb2 * TS + t) * HH + u] = hn;   // f32 output
      hcn[lb * 16 + ul]     = f2bf(hn);
      hcn[lb * 16 + 8 + ul] = f2bf(cn);
    }
    __syncthreads();

    // ---- publish h (bf16, coalesced) + z1 k-partials for step t+1 ----
    if (tid < 64) {  // h only: hbuf[(t+1)&1][batch][js*8..+8]
      int lb = tid >> 1, half = tid & 1;
      ull pk = *(const ull*)&hcn[lb * 16 + half * 4];
      ull* hp = (ull*)(p.hbuf
                + (((size_t)((t + 1) & 1)) * BB + bg * 32 + lb) * HH + js * 8);
      st64(hp + half, pk);
    }
    {  // z1p[batch][js][s]: exact 16-k partial via 14 MFMAs/block.
       // A = hcn[m][k] (k<16 real, K 16..31 zero), B = W1sl[s][k] (R5 pattern)
      int mt  = wv & 1;
      int nt0 = (wv >> 1) * 4;
      int ntn = (wv >> 1) ? 3 : 4;      // waves 0,1: s-tiles 0..3; 2,3: 4..6
      s8v zero8 = {0, 0, 0, 0, 0, 0, 0, 0};
      s8v av = zero8;
      if (q8 < 16) av = *(const s8v*)&hcn[(mt * 16 + m15) * 16 + q8];
      for (int u2 = 0; u2 < ntn; ++u2) {
        int nt = nt0 + u2;
        s8v bv = zero8;
        if (q8 < 16) bv = *(const s8v*)&W1sl[(nt * 16 + m15) * 16 + q8];
        f4 zacc = {0.f, 0.f, 0.f, 0.f};
        zacc = __builtin_amdgcn_mfma_f32_16x16x32_bf16(av, bv, zacc, 0, 0, 0);
        // C: col=lane&15 -> s_local, row=(lane>>4)*4+i -> batch_local
        int m0   = mt * 16 + (lane >> 4) * 4;
        int scol = nt * 16 + m15;
        float* zb = p.z1p + ((size_t)(bg * 32 + m0) * 32 + js) * 112 + scol;
        #pragma unroll
        for (int i = 0; i < 4; ++i)
          stf(zb + (size_t)i * 32 * 112, zacc[i]);   // 16-lane 64B-aligned runs
      }
    }
    __builtin_amdgcn_s_waitcnt(0);   // drain this wave's h/z1p stores
    __syncthreads();                 // all waves drained
    if (tid == 0)
      __hip_atomic_fetch_add(&p.flagB[bg], 1u, __ATOMIC_RELAXED,
                             __HIP_MEMORY_SCOPE_AGENT);
  }
}

extern "C" void kernel_launch(void* const* d_in, const int* in_sizes, int n_in,
                              void* d_out, int out_size, void* d_ws, size_t ws_size,
                              hipStream_t stream)
{
  KParams p;
  p.in  = (const float*)d_in[0];
  p.W1  = (const float*)d_in[1];
  p.b1  = (const float*)d_in[2];
  p.W2  = (const float*)d_in[3];
  p.b2  = (const float*)d_in[4];
  p.W3  = (const float*)d_in[5];
  // d_in[6] = b3: softmax shift-invariant, unused
  p.Wih = (const float*)d_in[7];
  p.Whh = (const float*)d_in[8];
  p.bih = (const float*)d_in[9];
  p.bhh = (const float*)d_in[10];
  p.out = (float*)d_out;

  char* ws = (char*)d_ws;
  const size_t offFlagB  = 2048;
  const size_t offHbuf   = 4096;
  const size_t hbufBytes = 2ull * BB * HH * 2;                 // 524,288
  const size_t offWbf    = offHbuf + hbufBytes;                // 528,384
  const size_t wbfBytes  = (size_t)BB * NN * 2;                // 131,072
  const size_t offZ1p    = offWbf + wbfBytes;                  // 659,456
  const size_t z1pBytes  = (size_t)BB * 32 * 112 * 4;          // 7,340,032
  const size_t needBytes = offZ1p + z1pBytes;                  // ~8.0 MB
  if (ws_size < needBytes) return;  // fail loudly (poisoned output)

  p.flagA = (uint32*)ws;
  p.flagB = (uint32*)(ws + offFlagB);
  p.hbuf  = (u16*)(ws + offHbuf);
  p.wbf   = (u16*)(ws + offWbf);
  p.z1p   = (float*)(ws + offZ1p);

  // zero flags + hbuf (+wbf); z1p is written-before-read each iteration
  hipMemsetAsync(d_ws, 0, offZ1p, stream);

  enc_kernel<<<dim3(512), dim3(256), 0, stream>>>(p);
}